// Round 1
// baseline (1503.957 us; speedup 1.0000x reference)
//
#include <hip/hip_runtime.h>
#include <math.h>

#define NB     32768   // B*T samples
#define NNODE  12
#define HID    32
#define HEADS  4
#define CH     128
#define TT     1024
#define BBATCH 32
#define SPB    32      // samples per block in k_main

// ws layout:
// [0,    512)  : stats1 double[64]  (sum[32], sumsq[32])
// [512, 2560)  : stats2 double[256] (sum[128], sumsq[128])
// [4096, 4096+NB*CH*4) : z float[NB*128]

__global__ __launch_bounds__(256) void k_stats1(
    const float* __restrict__ x, const float* __restrict__ adj,
    const float* __restrict__ W0, const float* __restrict__ b0,
    double* __restrict__ stats1)
{
    __shared__ float adjL[144];
    __shared__ double redS[256], redQ[256];
    int tid = threadIdx.x;
    for (int i = tid; i < 144; i += 256) adjL[i] = adj[i];
    __syncthreads();
    int f = tid & 31, slot = tid >> 5;
    float w0a = W0[f], w0b = W0[32 + f], b0f = b0[f];
    double aS = 0.0, aQ = 0.0;
    for (int s = blockIdx.x * 8 + slot; s < NB; s += gridDim.x * 8) {
        const float* xp = x + (size_t)s * 24;
        float t0[12];
#pragma unroll
        for (int m = 0; m < 12; m++) t0[m] = xp[m * 2] * w0a + xp[m * 2 + 1] * w0b;
#pragma unroll
        for (int n = 0; n < 12; n++) {
            float y = b0f;
#pragma unroll
            for (int m = 0; m < 12; m++) y += adjL[n * 12 + m] * t0[m];
            aS += y; aQ += (double)y * y;
        }
    }
    redS[tid] = aS; redQ[tid] = aQ;
    __syncthreads();
    if (tid < 32) {
        for (int sl = 1; sl < 8; sl++) { aS += redS[sl * 32 + tid]; aQ += redQ[sl * 32 + tid]; }
        atomicAdd(&stats1[tid], aS);
        atomicAdd(&stats1[32 + tid], aQ);
    }
}

__global__ __launch_bounds__(384) void k_main(
    const float* __restrict__ x, const float* __restrict__ adj,
    const float* __restrict__ W0, const float* __restrict__ b0,
    const float* __restrict__ W1, const float* __restrict__ b1,
    const float* __restrict__ Wr, const float* __restrict__ br,
    const float* __restrict__ g_bn, const float* __restrict__ be_bn,
    const float* __restrict__ Watt, const float* __restrict__ a_l,
    const float* __restrict__ a_r, const float* __restrict__ Wmh,
    const float* __restrict__ Wc,
    const double* __restrict__ stats1, float* __restrict__ zout)
{
    __shared__ float adjL[144], W0L[64], WrL[64], W1L[1024], WattL[4096], WmhL[5120];
    __shared__ float alL[128], arL[128];
    __shared__ float b0L[32], b1L[32], brL[32], gbnL[32], bebnL[32], mean1L[32], rstd1L[32];
    __shared__ float xsL[24];
    __shared__ float bufA[384];   // t0 / t1 / z-partials
    __shared__ float bufB[384];   // post-BN y / hout
    __shared__ float h2L[384];
    __shared__ float WhL[1536];   // [4][12][32]
    __shared__ float hplL[1536];  // [12][128] head-major
    __shared__ float attL[576];   // [4][12][12]
    __shared__ float elrL[96];    // el[4][12], er[4][12]

    int tid = threadIdx.x;
    for (int i = tid; i < 144; i += 384) adjL[i] = adj[i];
    for (int i = tid; i < 64; i += 384) { W0L[i] = W0[i]; WrL[i] = Wr[i]; }
    for (int i = tid; i < 1024; i += 384) W1L[i] = W1[i];
    for (int i = tid; i < 4096; i += 384) WattL[i] = Watt[i];
    for (int i = tid; i < 5120; i += 384) WmhL[i] = Wmh[i];
    for (int i = tid; i < 128; i += 384) { alL[i] = a_l[i]; arL[i] = a_r[i]; }
    if (tid < 32) {
        b0L[tid] = b0[tid]; b1L[tid] = b1[tid]; brL[tid] = br[tid];
        gbnL[tid] = g_bn[tid]; bebnL[tid] = be_bn[tid];
        double cnt = (double)NB * NNODE;
        double m = stats1[tid] / cnt;
        double var = stats1[32 + tid] / cnt - m * m;
        mean1L[tid] = (float)m;
        rstd1L[tid] = (float)(1.0 / sqrt(var + 1e-5));
    }
    __syncthreads();

    int n = tid >> 5, f = tid & 31;
    int s0 = blockIdx.x * SPB;
    for (int sl = 0; sl < SPB; ++sl) {
        int s = s0 + sl;
        if (tid < 24) xsL[tid] = x[(size_t)s * 24 + tid];
        __syncthreads();

        float xa = xsL[n * 2], xb = xsL[n * 2 + 1];
        float res = xa * WrL[f] + xb * WrL[32 + f] + brL[f];
        bufA[tid] = xa * W0L[f] + xb * W0L[32 + f];
        __syncthreads();

        float y = b0L[f];
#pragma unroll
        for (int m = 0; m < 12; m++) y += adjL[n * 12 + m] * bufA[m * 32 + f];
        y = (y - mean1L[f]) * rstd1L[f] * gbnL[f] + bebnL[f];
        y = fmaxf(y, 0.f);
        bufB[tid] = y;
        __syncthreads();

        float t1 = 0.f;
#pragma unroll
        for (int k = 0; k < 32; k++) t1 += bufB[n * 32 + k] * W1L[k * 32 + f];
        bufA[tid] = t1;
        __syncthreads();

        float y1 = b1L[f];
#pragma unroll
        for (int m = 0; m < 12; m++) y1 += adjL[n * 12 + m] * bufA[m * 32 + f];
        float h2v = y1 + res;
        h2L[tid] = h2v;
        __syncthreads();

#pragma unroll
        for (int hh = 0; hh < 4; hh++) {
            float w = 0.f;
#pragma unroll
            for (int k = 0; k < 32; k++) w += h2L[n * 32 + k] * WattL[hh * 1024 + k * 32 + f];
            WhL[hh * 384 + n * 32 + f] = w;
        }
        __syncthreads();

        if (tid < 96) {
            int type = tid / 48, r = tid % 48, hh = r / 12, nn = r % 12;
            const float* av = type ? arL : alL;
            float acc = 0.f;
#pragma unroll
            for (int o = 0; o < 32; o++) acc += WhL[hh * 384 + nn * 32 + o] * av[hh * 32 + o];
            elrL[tid] = acc;
        }
        __syncthreads();

        if (tid < 48) {
            int hh = tid / 12, nn = tid % 12;
            float el = elrL[hh * 12 + nn];
            float ev[12]; float mx = -1e30f;
#pragma unroll
            for (int m = 0; m < 12; m++) {
                float e = el + elrL[48 + hh * 12 + m];
                e = e > 0.f ? e : 0.01f * e;
                ev[m] = e; mx = fmaxf(mx, e);
            }
            float sum = 0.f;
#pragma unroll
            for (int m = 0; m < 12; m++) { ev[m] = __expf(ev[m] - mx); sum += ev[m]; }
            float inv = 1.f / sum;
#pragma unroll
            for (int m = 0; m < 12; m++) attL[hh * 144 + nn * 12 + m] = ev[m] * inv;
        }
        __syncthreads();

#pragma unroll
        for (int hh = 0; hh < 4; hh++) {
            float acc = 0.f;
#pragma unroll
            for (int m = 0; m < 12; m++) acc += attL[hh * 144 + n * 12 + m] * WhL[hh * 384 + m * 32 + f];
            hplL[n * 128 + hh * 32 + f] = acc;
        }
        __syncthreads();

        float ho = 0.f;
#pragma unroll
        for (int k = 0; k < 32; k++) ho += h2L[n * 32 + k] * WmhL[k * 32 + f];
#pragma unroll
        for (int j = 0; j < 128; j++) ho += hplL[n * 128 + j] * WmhL[(32 + j) * 32 + f];
        bufB[tid] = ho;   // hout, flat [12*32]
        __syncthreads();

        {
            int ch = tid & 127, seg = tid >> 7;
            const float* wc = Wc + (size_t)ch * 384 + seg * 128;
            const float* hb = bufB + seg * 128;
            float p = 0.f;
#pragma unroll 8
            for (int j = 0; j < 128; j++) p += hb[j] * wc[j];
            bufA[tid] = p;
            __syncthreads();
            if (tid < 128) {
                float zv = bufA[tid] + bufA[128 + tid] + bufA[256 + tid];
                zout[(size_t)s * 128 + tid] = zv;
            }
        }
        __syncthreads();
    }
}

__global__ __launch_bounds__(256) void k_stats2(
    const float* __restrict__ z, double* __restrict__ stats2)
{
    __shared__ double redS[256], redQ[256];
    int tid = threadIdx.x; int ch = tid & 127, slot = tid >> 7;
    double aS = 0, aQ = 0;
    for (int s = blockIdx.x * 2 + slot; s < NB; s += gridDim.x * 2) {
        float v = z[(size_t)s * 128 + ch];
        aS += v; aQ += (double)v * v;
    }
    redS[tid] = aS; redQ[tid] = aQ;
    __syncthreads();
    if (tid < 128) {
        aS = redS[tid] + redS[128 + tid];
        aQ = redQ[tid] + redQ[128 + tid];
        atomicAdd(&stats2[tid], aS);
        atomicAdd(&stats2[128 + tid], aQ);
    }
}

__global__ __launch_bounds__(128) void k_final(
    const float* __restrict__ z, const double* __restrict__ stats2,
    const float* __restrict__ g2, const float* __restrict__ be2,
    const float* __restrict__ Wl, const float* __restrict__ bl,
    float* __restrict__ out)
{
    __shared__ float poolL[128];
    int ch = threadIdx.x;
    double cnt = (double)NB;
    double m = stats2[ch] / cnt;
    double var = stats2[128 + ch] / cnt - m * m;
    float mean = (float)m, rstd = (float)(1.0 / sqrt(var + 1e-5));
    float g = g2[ch], be = be2[ch];
    const float* zp = z + (size_t)blockIdx.x * TT * CH + ch;
    float acc = 0.f;
    for (int t = 0; t < TT; t++) {
        float v = zp[t * CH];
        v = (v - mean) * rstd * g + be;
        acc += fmaxf(v, 0.f);
    }
    poolL[ch] = acc * (1.0f / TT);
    __syncthreads();
    if (ch < 10) {
        float o = bl[ch];
        for (int c = 0; c < 128; c++) o += poolL[c] * Wl[c * 10 + ch];
        out[blockIdx.x * 10 + ch] = o;
    }
}

extern "C" void kernel_launch(void* const* d_in, const int* in_sizes, int n_in,
                              void* d_out, int out_size, void* d_ws, size_t ws_size,
                              hipStream_t stream)
{
    const float* x    = (const float*)d_in[0];
    const float* adj  = (const float*)d_in[1];
    const float* W0   = (const float*)d_in[2];
    const float* b0   = (const float*)d_in[3];
    const float* W1   = (const float*)d_in[4];
    const float* b1   = (const float*)d_in[5];
    const float* Wr   = (const float*)d_in[6];
    const float* br   = (const float*)d_in[7];
    const float* gbn  = (const float*)d_in[8];
    const float* bebn = (const float*)d_in[9];
    const float* Watt = (const float*)d_in[10];
    const float* al   = (const float*)d_in[11];
    const float* ar   = (const float*)d_in[12];
    const float* Wmh  = (const float*)d_in[13];
    const float* Wc   = (const float*)d_in[14];
    const float* g2   = (const float*)d_in[15];
    const float* be2  = (const float*)d_in[16];
    const float* Wl   = (const float*)d_in[17];
    const float* bl   = (const float*)d_in[18];
    float* out = (float*)d_out;

    double* stats1 = (double*)d_ws;
    double* stats2 = (double*)((char*)d_ws + 512);
    float*  z      = (float*)((char*)d_ws + 4096);

    hipMemsetAsync(d_ws, 0, 4096, stream);
    k_stats1<<<512, 256, 0, stream>>>(x, adj, W0, b0, stats1);
    k_main<<<NB / SPB, 384, 0, stream>>>(x, adj, W0, b0, W1, b1, Wr, br, gbn, bebn,
                                         Watt, al, ar, Wmh, Wc, stats1, z);
    k_stats2<<<256, 256, 0, stream>>>(z, stats2);
    k_final<<<BBATCH, 128, 0, stream>>>(z, stats2, g2, be2, Wl, bl, out);
}

// Round 2
// 1260.175 us; speedup vs baseline: 1.1935x; 1.1935x over previous
//
#include <hip/hip_runtime.h>
#include <math.h>

#define NB     32768
#define TT     1024
#define BBATCH 32

// ws layout:
// [0,512)     stats1 double[64]
// [512,2560)  stats2 double[256]
// [4096, +16MB)           z float[NB*128]
// [4096+16MB, +48MB)      hout float[NB*384]
#define Z_OFF    4096
#define HOUT_OFF (4096 + (size_t)NB * 128 * 4)

__global__ __launch_bounds__(256) void k_stats1(
    const float* __restrict__ x, const float* __restrict__ adj,
    const float* __restrict__ W0, const float* __restrict__ b0,
    double* __restrict__ stats1)
{
    __shared__ float adjL[144];
    __shared__ double redS[256], redQ[256];
    int tid = threadIdx.x;
    for (int i = tid; i < 144; i += 256) adjL[i] = adj[i];
    __syncthreads();
    int f = tid & 31, slot = tid >> 5;
    float w0a = W0[f], w0b = W0[32 + f], b0f = b0[f];
    double aS = 0.0, aQ = 0.0;
    for (int s = blockIdx.x * 8 + slot; s < NB; s += gridDim.x * 8) {
        const float* xp = x + (size_t)s * 24;
        float t0[12];
#pragma unroll
        for (int m = 0; m < 12; m++) t0[m] = xp[m * 2] * w0a + xp[m * 2 + 1] * w0b;
#pragma unroll
        for (int n = 0; n < 12; n++) {
            float y = b0f;
#pragma unroll
            for (int m = 0; m < 12; m++) y += adjL[n * 12 + m] * t0[m];
            aS += y; aQ += (double)y * y;
        }
    }
    redS[tid] = aS; redQ[tid] = aQ;
    __syncthreads();
    if (tid < 32) {
        for (int sl = 1; sl < 8; sl++) { aS += redS[sl * 32 + tid]; aQ += redQ[sl * 32 + tid]; }
        atomicAdd(&stats1[tid], aS);
        atomicAdd(&stats1[32 + tid], aQ);
    }
}

// ---------------- k_main: one wave per sample chain, no barriers in loop ----
__global__ __launch_bounds__(768, 3) void k_main(
    const float* __restrict__ x, const float* __restrict__ adj,
    const float* __restrict__ W0, const float* __restrict__ b0,
    const float* __restrict__ W1, const float* __restrict__ b1,
    const float* __restrict__ Wr, const float* __restrict__ br,
    const float* __restrict__ g_bn, const float* __restrict__ be_bn,
    const float* __restrict__ Watt, const float* __restrict__ a_l,
    const float* __restrict__ a_r, const float* __restrict__ Wmh,
    const double* __restrict__ stats1, float* __restrict__ houtG)
{
    __shared__ __align__(16) float adjL[192];    // [12][16]
    __shared__ __align__(16) float W1L[1024];
    __shared__ __align__(16) float WattL[4096];
    __shared__ __align__(16) float WmhL[5120];
    __shared__ __align__(16) float vaL[288];     // [8][36]
    __shared__ __align__(16) float hbufS[12][432];   // per-wave [12 nodes][36]
    __shared__ __align__(16) float eS[12][112];      // el[48] | er[4][16]
    __shared__ __align__(16) float bigS[12][1536];   // att[48][12] then hpl[12][128]

    const int tid = threadIdx.x;
    if (tid < 144) adjL[(tid / 12) * 16 + (tid % 12)] = adj[tid];
    for (int i = tid; i < 1024; i += 768) W1L[i] = W1[i];
    for (int i = tid; i < 4096; i += 768) WattL[i] = Watt[i];
    for (int i = tid; i < 5120; i += 768) WmhL[i] = Wmh[i];
    __syncthreads();
    if (tid < 256) {   // va[type][h][k] = sum_o Watt[h][k][o] * a[h][o]
        int type = tid >> 7, h = (tid >> 5) & 3, k = tid & 31;
        const float* av = type ? a_r : a_l;
        float acc = 0.f;
        for (int o = 0; o < 32; o++) acc += WattL[h * 1024 + k * 32 + o] * av[h * 32 + o];
        vaL[(type * 4 + h) * 36 + k] = acc;
    }
    __syncthreads();

    const int lane = tid & 63;
    const int wv = tid >> 6;
    const int f = lane & 31;
    const int p = lane >> 5;      // node parity this lane owns: n = p + 2j
    float* hbuf = hbufS[wv];
    float* eW = eS[wv];
    float* bigW = bigS[wv];

    const float W0c0 = W0[f], W0c1 = W0[32 + f];
    const float Wrc0 = Wr[f], Wrc1 = Wr[32 + f];
    const float brc = br[f], b0c = b0[f], b1c = b1[f];
    double cnt = (double)NB * 12.0;
    double m1 = stats1[f] / cnt;
    double v1 = stats1[32 + f] / cnt - m1 * m1;
    const float sc1 = (float)((double)g_bn[f] / sqrt(v1 + 1e-5));
    const float sh1 = be_bn[f] - (float)m1 * sc1;

    int gw = blockIdx.x * 12 + wv;       // 3072 waves; 32768 = 2048*11 + 1024*10
    int base, count;
    if (gw < 2048) { count = 11; base = gw * 11; }
    else           { count = 10; base = 22528 + (gw - 2048) * 10; }

    float2 xv[6];
#pragma unroll
    for (int j = 0; j < 6; j++)
        xv[j] = *(const float2*)&x[(size_t)base * 24 + (p + 2 * j) * 2];

    for (int si = 0; si < count; si++) {
        const int s = base + si;
        const int sn = (si + 1 < count) ? s + 1 : s;
        float2 xn[6];
#pragma unroll
        for (int j = 0; j < 6; j++)
            xn[j] = *(const float2*)&x[(size_t)sn * 24 + (p + 2 * j) * 2];

        // t0 = x@W0 (own nodes), residual
        float t0[6], res[6];
#pragma unroll
        for (int j = 0; j < 6; j++) {
            t0[j]  = xv[j].x * W0c0 + xv[j].y * W0c1;
            res[j] = xv[j].x * Wrc0 + xv[j].y * Wrc1 + brc;
        }
        float t0all[12];
#pragma unroll
        for (int j = 0; j < 6; j++) {
            float o = __shfl_xor(t0[j], 32);
            t0all[2 * j]     = p ? o : t0[j];
            t0all[2 * j + 1] = p ? t0[j] : o;
        }
        // GCN0 adj-mix + BN + ReLU -> y rows to LDS
#pragma unroll
        for (int j = 0; j < 6; j++) {
            const float* arow = &adjL[(p + 2 * j) * 16];
            float acc = b0c;
#pragma unroll
            for (int m4 = 0; m4 < 3; m4++) {
                float4 a4 = *(const float4*)&arow[m4 * 4];
                acc += a4.x * t0all[m4 * 4] + a4.y * t0all[m4 * 4 + 1]
                     + a4.z * t0all[m4 * 4 + 2] + a4.w * t0all[m4 * 4 + 3];
            }
            hbuf[(p + 2 * j) * 36 + f] = fmaxf(acc * sc1 + sh1, 0.f);
        }
        // t1 = y @ W1
        float t1[6] = {0.f, 0.f, 0.f, 0.f, 0.f, 0.f};
#pragma unroll
        for (int k4 = 0; k4 < 8; k4++) {
            float4 h4[6];
#pragma unroll
            for (int j = 0; j < 6; j++) h4[j] = *(const float4*)&hbuf[(p + 2 * j) * 36 + k4 * 4];
#pragma unroll
            for (int kk = 0; kk < 4; kk++) {
                float w1v = W1L[(k4 * 4 + kk) * 32 + f];
                t1[0] += ((const float*)&h4[0])[kk] * w1v;
                t1[1] += ((const float*)&h4[1])[kk] * w1v;
                t1[2] += ((const float*)&h4[2])[kk] * w1v;
                t1[3] += ((const float*)&h4[3])[kk] * w1v;
                t1[4] += ((const float*)&h4[4])[kk] * w1v;
                t1[5] += ((const float*)&h4[5])[kk] * w1v;
            }
        }
        float t1all[12];
#pragma unroll
        for (int j = 0; j < 6; j++) {
            float o = __shfl_xor(t1[j], 32);
            t1all[2 * j]     = p ? o : t1[j];
            t1all[2 * j + 1] = p ? t1[j] : o;
        }
        // GCN1 + residual -> h2 (regs + LDS rows, overwrite y)
        float h2[6];
#pragma unroll
        for (int j = 0; j < 6; j++) {
            const float* arow = &adjL[(p + 2 * j) * 16];
            float acc = b1c;
#pragma unroll
            for (int m4 = 0; m4 < 3; m4++) {
                float4 a4 = *(const float4*)&arow[m4 * 4];
                acc += a4.x * t1all[m4 * 4] + a4.y * t1all[m4 * 4 + 1]
                     + a4.z * t1all[m4 * 4 + 2] + a4.w * t1all[m4 * 4 + 3];
            }
            h2[j] = acc + res[j];
        }
#pragma unroll
        for (int j = 0; j < 6; j++) hbuf[(p + 2 * j) * 36 + f] = h2[j];

        // Wh[h][n][f] = sum_k h2[n][k] Watt[h][k][f]
        float Wh[4][6];
#pragma unroll
        for (int h = 0; h < 4; h++)
#pragma unroll
            for (int j = 0; j < 6; j++) Wh[h][j] = 0.f;
#pragma unroll
        for (int k4 = 0; k4 < 8; k4++) {
            float4 h4[6];
#pragma unroll
            for (int j = 0; j < 6; j++) h4[j] = *(const float4*)&hbuf[(p + 2 * j) * 36 + k4 * 4];
#pragma unroll
            for (int kk = 0; kk < 4; kk++) {
                float wav0 = WattL[(k4 * 4 + kk) * 32 + f];
                float wav1 = WattL[1024 + (k4 * 4 + kk) * 32 + f];
                float wav2 = WattL[2048 + (k4 * 4 + kk) * 32 + f];
                float wav3 = WattL[3072 + (k4 * 4 + kk) * 32 + f];
#pragma unroll
                for (int j = 0; j < 6; j++) {
                    float hvv = ((const float*)&h4[j])[kk];
                    Wh[0][j] += hvv * wav0;
                    Wh[1][j] += hvv * wav1;
                    Wh[2][j] += hvv * wav2;
                    Wh[3][j] += hvv * wav3;
                }
            }
        }
        // el/er: 96 tasks, el[h][n]=sum_k h2[n][k]*va_l[h][k]
        {
            int t = lane;   // tasks 0..63
            int ty = t / 48, rr = t % 48, hh = rr / 12, nn = rr % 12;
            float acc = 0.f;
#pragma unroll
            for (int k4 = 0; k4 < 8; k4++) {
                float4 hv = *(const float4*)&hbuf[nn * 36 + k4 * 4];
                float4 vv = *(const float4*)&vaL[(ty * 4 + hh) * 36 + k4 * 4];
                acc += hv.x * vv.x + hv.y * vv.y + hv.z * vv.z + hv.w * vv.w;
            }
            eW[ty ? (48 + hh * 16 + nn) : (hh * 12 + nn)] = acc;
        }
        if (lane < 32) {    // tasks 64..95 (all type er)
            int rr = 16 + lane, hh = rr / 12, nn = rr % 12;
            float acc = 0.f;
#pragma unroll
            for (int k4 = 0; k4 < 8; k4++) {
                float4 hv = *(const float4*)&hbuf[nn * 36 + k4 * 4];
                float4 vv = *(const float4*)&vaL[(4 + hh) * 36 + k4 * 4];
                acc += hv.x * vv.x + hv.y * vv.y + hv.z * vv.z + hv.w * vv.w;
            }
            eW[48 + hh * 16 + nn] = acc;
        }
        // softmax rows (48 tasks) -> att into bigW[t*12+m]
        if (lane < 48) {
            int hh = lane / 12;
            float el = eW[lane >= 0 ? (hh * 12 + (lane % 12)) : 0];
            float ev[12];
            float mx = -1e30f;
#pragma unroll
            for (int m4 = 0; m4 < 3; m4++) {
                float4 er4 = *(const float4*)&eW[48 + hh * 16 + m4 * 4];
                float e0 = el + er4.x; e0 = e0 > 0.f ? e0 : 0.01f * e0;
                float e1 = el + er4.y; e1 = e1 > 0.f ? e1 : 0.01f * e1;
                float e2 = el + er4.z; e2 = e2 > 0.f ? e2 : 0.01f * e2;
                float e3 = el + er4.w; e3 = e3 > 0.f ? e3 : 0.01f * e3;
                ev[m4 * 4] = e0; ev[m4 * 4 + 1] = e1; ev[m4 * 4 + 2] = e2; ev[m4 * 4 + 3] = e3;
                mx = fmaxf(mx, fmaxf(fmaxf(e0, e1), fmaxf(e2, e3)));
            }
            float sum = 0.f;
#pragma unroll
            for (int m = 0; m < 12; m++) { float e = __expf(ev[m] - mx); ev[m] = e; sum += e; }
            float inv = 1.f / sum;
#pragma unroll
            for (int m4 = 0; m4 < 3; m4++) {
                float4 o;
                o.x = ev[m4 * 4] * inv; o.y = ev[m4 * 4 + 1] * inv;
                o.z = ev[m4 * 4 + 2] * inv; o.w = ev[m4 * 4 + 3] * inv;
                *(float4*)&bigW[lane * 12 + m4 * 4] = o;
            }
        }
        // hp[h][n][f] = sum_m att[h][n][m] Wh[h][m][f]
        float hp[4][6];
#pragma unroll
        for (int h = 0; h < 4; h++) {
            float Whall[12];
#pragma unroll
            for (int j = 0; j < 6; j++) {
                float o = __shfl_xor(Wh[h][j], 32);
                Whall[2 * j]     = p ? o : Wh[h][j];
                Whall[2 * j + 1] = p ? Wh[h][j] : o;
            }
#pragma unroll
            for (int j = 0; j < 6; j++) {
                const float* arow = &bigW[(h * 12 + (p + 2 * j)) * 12];
                float acc = 0.f;
#pragma unroll
                for (int m4 = 0; m4 < 3; m4++) {
                    float4 a4 = *(const float4*)&arow[m4 * 4];
                    acc += a4.x * Whall[m4 * 4] + a4.y * Whall[m4 * 4 + 1]
                         + a4.z * Whall[m4 * 4 + 2] + a4.w * Whall[m4 * 4 + 3];
                }
                hp[h][j] = acc;
            }
        }
        // write hpl (after all att reads; wave program-order safe)
#pragma unroll
        for (int h = 0; h < 4; h++)
#pragma unroll
            for (int j = 0; j < 6; j++)
                bigW[(p + 2 * j) * 128 + h * 32 + f] = hp[h][j];

        // hout = h2 @ Wmh[0:32] + hpl @ Wmh[32:160]
        float ho[6] = {0.f, 0.f, 0.f, 0.f, 0.f, 0.f};
#pragma unroll
        for (int k4 = 0; k4 < 8; k4++) {
            float4 h4[6];
#pragma unroll
            for (int j = 0; j < 6; j++) h4[j] = *(const float4*)&hbuf[(p + 2 * j) * 36 + k4 * 4];
#pragma unroll
            for (int kk = 0; kk < 4; kk++) {
                float wvv = WmhL[(k4 * 4 + kk) * 32 + f];
#pragma unroll
                for (int j = 0; j < 6; j++) ho[j] += ((const float*)&h4[j])[kk] * wvv;
            }
        }
#pragma unroll
        for (int q4 = 0; q4 < 32; q4++) {
            float4 p4[6];
#pragma unroll
            for (int j = 0; j < 6; j++) p4[j] = *(const float4*)&bigW[(p + 2 * j) * 128 + q4 * 4];
#pragma unroll
            for (int kk = 0; kk < 4; kk++) {
                float wvv = WmhL[(32 + q4 * 4 + kk) * 32 + f];
#pragma unroll
                for (int j = 0; j < 6; j++) ho[j] += ((const float*)&p4[j])[kk] * wvv;
            }
        }
#pragma unroll
        for (int j = 0; j < 6; j++)
            houtG[(size_t)s * 384 + (p + 2 * j) * 32 + f] = ho[j];

#pragma unroll
        for (int j = 0; j < 6; j++) xv[j] = xn[j];
    }
}

// ---------------- k_conv: z = hout[NB,384] @ Wc^T[384,128], tiled ----------
__global__ __launch_bounds__(512, 2) void k_conv(
    const float* __restrict__ hout, const float* __restrict__ Wc,
    float* __restrict__ z)
{
    __shared__ __align__(16) float sA[128 * 36];
    __shared__ __align__(16) float sB[128 * 36];
    const int tid = threadIdx.x;
    const int s0 = blockIdx.x * 128;
    const int tx = tid & 15;     // ch = tx + 16j
    const int ty = tid >> 4;     // s  = ty + 32i
    float acc[4][8];
#pragma unroll
    for (int i = 0; i < 4; i++)
#pragma unroll
        for (int j = 0; j < 8; j++) acc[i][j] = 0.f;

    for (int kc = 0; kc < 12; kc++) {
        const int k0 = kc * 32;
        {
            int r = tid >> 2, q = tid & 3;
            const float* ga = &hout[(size_t)(s0 + r) * 384 + k0 + q * 8];
            const float* gb = &Wc[(size_t)r * 384 + k0 + q * 8];
            float4 v0 = *(const float4*)&ga[0];
            float4 v1 = *(const float4*)&ga[4];
            float4 w0 = *(const float4*)&gb[0];
            float4 w1 = *(const float4*)&gb[4];
            *(float4*)&sA[r * 36 + q * 8]     = v0;
            *(float4*)&sA[r * 36 + q * 8 + 4] = v1;
            *(float4*)&sB[r * 36 + q * 8]     = w0;
            *(float4*)&sB[r * 36 + q * 8 + 4] = w1;
        }
        __syncthreads();
#pragma unroll
        for (int k4 = 0; k4 < 8; k4++) {
            float4 av[4], bv[8];
#pragma unroll
            for (int i = 0; i < 4; i++) av[i] = *(const float4*)&sA[(ty + 32 * i) * 36 + k4 * 4];
#pragma unroll
            for (int j = 0; j < 8; j++) bv[j] = *(const float4*)&sB[(tx + 16 * j) * 36 + k4 * 4];
#pragma unroll
            for (int i = 0; i < 4; i++)
#pragma unroll
                for (int j = 0; j < 8; j++)
                    acc[i][j] += av[i].x * bv[j].x + av[i].y * bv[j].y
                               + av[i].z * bv[j].z + av[i].w * bv[j].w;
        }
        __syncthreads();
    }
#pragma unroll
    for (int i = 0; i < 4; i++)
#pragma unroll
        for (int j = 0; j < 8; j++)
            z[(size_t)(s0 + ty + 32 * i) * 128 + tx + 16 * j] = acc[i][j];
}

__global__ __launch_bounds__(256) void k_stats2(
    const float* __restrict__ z, double* __restrict__ stats2)
{
    __shared__ double redS[256], redQ[256];
    int tid = threadIdx.x; int ch = tid & 127, slot = tid >> 7;
    double aS = 0, aQ = 0;
    for (int s = blockIdx.x * 2 + slot; s < NB; s += gridDim.x * 2) {
        float v = z[(size_t)s * 128 + ch];
        aS += v; aQ += (double)v * v;
    }
    redS[tid] = aS; redQ[tid] = aQ;
    __syncthreads();
    if (tid < 128) {
        aS = redS[tid] + redS[128 + tid];
        aQ = redQ[tid] + redQ[128 + tid];
        atomicAdd(&stats2[tid], aS);
        atomicAdd(&stats2[128 + tid], aQ);
    }
}

__global__ __launch_bounds__(128) void k_final(
    const float* __restrict__ z, const double* __restrict__ stats2,
    const float* __restrict__ g2, const float* __restrict__ be2,
    const float* __restrict__ Wl, const float* __restrict__ bl,
    float* __restrict__ out)
{
    __shared__ float poolL[128];
    int ch = threadIdx.x;
    double cnt = (double)NB;
    double m = stats2[ch] / cnt;
    double var = stats2[128 + ch] / cnt - m * m;
    float mean = (float)m, rstd = (float)(1.0 / sqrt(var + 1e-5));
    float g = g2[ch], be = be2[ch];
    const float* zp = z + (size_t)blockIdx.x * TT * 128 + ch;
    float acc = 0.f;
    for (int t = 0; t < TT; t++) {
        float v = zp[t * 128];
        v = (v - mean) * rstd * g + be;
        acc += fmaxf(v, 0.f);
    }
    poolL[ch] = acc * (1.0f / TT);
    __syncthreads();
    if (ch < 10) {
        float o = bl[ch];
        for (int c = 0; c < 128; c++) o += poolL[c] * Wl[c * 10 + ch];
        out[blockIdx.x * 10 + ch] = o;
    }
}

extern "C" void kernel_launch(void* const* d_in, const int* in_sizes, int n_in,
                              void* d_out, int out_size, void* d_ws, size_t ws_size,
                              hipStream_t stream)
{
    const float* x    = (const float*)d_in[0];
    const float* adj  = (const float*)d_in[1];
    const float* W0   = (const float*)d_in[2];
    const float* b0   = (const float*)d_in[3];
    const float* W1   = (const float*)d_in[4];
    const float* b1   = (const float*)d_in[5];
    const float* Wr   = (const float*)d_in[6];
    const float* br   = (const float*)d_in[7];
    const float* gbn  = (const float*)d_in[8];
    const float* bebn = (const float*)d_in[9];
    const float* Watt = (const float*)d_in[10];
    const float* al   = (const float*)d_in[11];
    const float* ar   = (const float*)d_in[12];
    const float* Wmh  = (const float*)d_in[13];
    const float* Wc   = (const float*)d_in[14];
    const float* g2   = (const float*)d_in[15];
    const float* be2  = (const float*)d_in[16];
    const float* Wl   = (const float*)d_in[17];
    const float* bl   = (const float*)d_in[18];
    float* out = (float*)d_out;

    double* stats1 = (double*)d_ws;
    double* stats2 = (double*)((char*)d_ws + 512);
    float*  z      = (float*)((char*)d_ws + Z_OFF);
    float*  houtG  = (float*)((char*)d_ws + HOUT_OFF);

    hipMemsetAsync(d_ws, 0, 4096, stream);
    k_stats1<<<512, 256, 0, stream>>>(x, adj, W0, b0, stats1);
    k_main<<<256, 768, 0, stream>>>(x, adj, W0, b0, W1, b1, Wr, br, gbn, bebn,
                                    Watt, al, ar, Wmh, stats1, houtG);
    k_conv<<<NB / 128, 512, 0, stream>>>(houtG, Wc, z);
    k_stats2<<<256, 256, 0, stream>>>(z, stats2);
    k_final<<<BBATCH, 128, 0, stream>>>(z, stats2, g2, be2, Wl, bl, out);
}